// Round 1
// baseline (3082.917 us; speedup 1.0000x reference)
//
#include <hip/hip_runtime.h>
#include <cstdint>
#include <cstddef>

typedef __bf16 bf16;
typedef __bf16 bf16x8 __attribute__((ext_vector_type(8)));
typedef float f32x4 __attribute__((ext_vector_type(4)));

#define SEQ 2048
#define DIM 4096
#define NHEAD 16
#define HDIM 256
#define DFF_N 16384
#define D3 12288

// ---------------- fused LayerNorm (ln1 + ln2) ----------------
__global__ __launch_bounds__(256) void ln_kernel(
    const float* __restrict__ x,
    const float* __restrict__ w1, const float* __restrict__ b1,
    const float* __restrict__ w2, const float* __restrict__ b2,
    bf16* __restrict__ x1, bf16* __restrict__ x2)
{
  int row = blockIdx.x;
  int t = threadIdx.x;
  const float* xr = x + (size_t)row * DIM + t * 16;
  float v[16];
  float s = 0.f, sq = 0.f;
#pragma unroll
  for (int i = 0; i < 4; i++) {
    float4 f = ((const float4*)xr)[i];
    v[i*4+0] = f.x; v[i*4+1] = f.y; v[i*4+2] = f.z; v[i*4+3] = f.w;
  }
#pragma unroll
  for (int i = 0; i < 16; i++) { s += v[i]; sq += v[i]*v[i]; }
#pragma unroll
  for (int o = 32; o; o >>= 1) { s += __shfl_xor(s, o, 64); sq += __shfl_xor(sq, o, 64); }
  __shared__ float rs[4], rq[4];
  int wave = t >> 6, lane = t & 63;
  if (lane == 0) { rs[wave] = s; rq[wave] = sq; }
  __syncthreads();
  s  = rs[0] + rs[1] + rs[2] + rs[3];
  sq = rq[0] + rq[1] + rq[2] + rq[3];
  float mean = s * (1.f/DIM);
  float var  = sq * (1.f/DIM) - mean*mean;
  float rstd = rsqrtf(var + 1e-5f);
  int c0 = t*16;
#pragma unroll
  for (int i = 0; i < 16; i++) {
    int c = c0 + i;
    float nv = (v[i] - mean) * rstd;
    x1[(size_t)row*DIM + c] = (bf16)(nv * w1[c] + b1[c]);
    x2[(size_t)row*DIM + c] = (bf16)(nv * w2[c] + b2[c]);
  }
}

// ---------------- GEMM: C = A(bf16,[M,K]) * B(f32,[K,N]) + bias, epilogues ----
// EPI: 0 = bias -> bf16     (QKV)
//      1 = bias -> f32      (dense -> dense_out)
//      2 = bias+gelu -> bf16 (fc1 -> h1)
//      3 = bias+add1+add2 -> f32 (fc2 -> d_out, add1=dense_out, add2=hidden)
template <int EPI>
__global__ __launch_bounds__(256) void gemm_kernel(
    const bf16* __restrict__ A, const float* __restrict__ B,
    const float* __restrict__ bias,
    const float* __restrict__ add1, const float* __restrict__ add2,
    void* __restrict__ Cout, int M, int N, int K)
{
  // As rows padded to 40 bf16 (80 B): keeps 16B alignment for ds_read_b128,
  // spreads the 16-row fragment read across banks (2-way only).
  __shared__ __align__(16) bf16 As[128][40];
  // Bs padded to 129 floats: fragment read bank = (k + n) % 32 -> 2-way.
  __shared__ float Bs[32][129];
  const int t = threadIdx.x;
  const int lane = t & 63;
  const int wave = t >> 6;
  const int l15 = lane & 15, l4 = lane >> 4;
  const int m0 = blockIdx.x * 128;   // M-tile fastest -> blocks sharing B panel co-resident
  const int n0 = blockIdx.y * 128;
  const int wm = (wave >> 1) * 64;
  const int wn = (wave & 1) * 64;

  f32x4 acc[4][4];
#pragma unroll
  for (int i = 0; i < 4; i++)
#pragma unroll
    for (int j = 0; j < 4; j++) acc[i][j] = (f32x4){0.f, 0.f, 0.f, 0.f};

  for (int k0 = 0; k0 < K; k0 += 32) {
    // stage A tile: 128 x 32 bf16, 16B per thread x2
#pragma unroll
    for (int i = 0; i < 2; i++) {
      int c = t + i * 256;
      int row = c >> 2, seg = c & 3;
      *(bf16x8*)&As[row][seg * 8] =
          *(const bf16x8*)(A + (size_t)(m0 + row) * K + k0 + seg * 8);
    }
    // stage B tile: 32 x 128 f32, float4 per thread x4
#pragma unroll
    for (int i = 0; i < 4; i++) {
      int c = t + i * 256;
      int kr = c >> 5, ns = c & 31;
      float4 bv = *(const float4*)(B + (size_t)(k0 + kr) * N + n0 + ns * 4);
      Bs[kr][ns*4+0] = bv.x; Bs[kr][ns*4+1] = bv.y;
      Bs[kr][ns*4+2] = bv.z; Bs[kr][ns*4+3] = bv.w;
    }
    __syncthreads();

    bf16x8 af[4];
#pragma unroll
    for (int mi = 0; mi < 4; mi++)
      af[mi] = *(const bf16x8*)&As[wm + mi * 16 + l15][l4 * 8];
#pragma unroll
    for (int ni = 0; ni < 4; ni++) {
      bf16x8 bfv;
#pragma unroll
      for (int j = 0; j < 8; j++)
        bfv[j] = (bf16)Bs[l4 * 8 + j][wn + ni * 16 + l15];
#pragma unroll
      for (int mi = 0; mi < 4; mi++)
        acc[mi][ni] = __builtin_amdgcn_mfma_f32_16x16x32_bf16(af[mi], bfv, acc[mi][ni], 0, 0, 0);
    }
    __syncthreads();
  }

  // epilogue; D layout: col = lane&15, row = (lane>>4)*4 + r  [verified m89/m91]
#pragma unroll
  for (int mi = 0; mi < 4; mi++) {
#pragma unroll
    for (int ni = 0; ni < 4; ni++) {
#pragma unroll
      for (int r = 0; r < 4; r++) {
        int m = m0 + wm + mi * 16 + l4 * 4 + r;
        int n = n0 + wn + ni * 16 + l15;
        size_t idx = (size_t)m * N + n;
        float val = acc[mi][ni][r] + bias[n];
        if (EPI == 0) {
          ((bf16*)Cout)[idx] = (bf16)val;
        } else if (EPI == 1) {
          ((float*)Cout)[idx] = val;
        } else if (EPI == 2) {
          // gelu_new (tanh approx); tanh via 1 - 2/(e^{2u}+1), overflow-safe
          float u = 0.7978845608028654f * (val + 0.044715f * val * val * val);
          float e = __expf(2.f * u);
          float th = 1.f - 2.f / (e + 1.f);
          ((bf16*)Cout)[idx] = (bf16)(0.5f * val * (1.f + th));
        } else {
          ((float*)Cout)[idx] = val + add1[idx] + add2[idx];
        }
      }
    }
  }
}

// ---------------- causal attention, one (16-query tile, head) per block ------
// LDS: scores fp32 [16][2049] (131 KB, dynamic) + inv_sum[16]
__global__ __launch_bounds__(256) void attn_kernel(
    const bf16* __restrict__ qkv, bf16* __restrict__ attn)
{
  extern __shared__ float smem[];
  float (*sc)[2049] = (float (*)[2049])smem;
  float* inv = smem + 16 * 2049;

  const int qt = blockIdx.x;   // 0..127
  const int h  = blockIdx.y;   // 0..15
  const int q0 = qt * 16;
  const int t = threadIdx.x;
  const int lane = t & 63, w = t >> 6;
  const int l15 = lane & 15, l4 = lane >> 4;

  // Q fragments (A-operand layout: m = lane&15, k = (lane>>4)*8 + j)
  bf16x8 qf[8];
  {
    const bf16* qbase = qkv + (size_t)(q0 + l15) * D3 + h * HDIM + l4 * 8;
#pragma unroll
    for (int dt = 0; dt < 8; dt++)
      qf[dt] = *(const bf16x8*)(qbase + dt * 32);
  }

  // ---- scores: waves split key tiles round-robin ----
  for (int kt = w; kt <= qt; kt += 4) {
    int k0 = kt * 16;
    f32x4 a = (f32x4){0.f, 0.f, 0.f, 0.f};
    const bf16* kbase = qkv + (size_t)(k0 + l15) * D3 + DIM + h * HDIM + l4 * 8;
#pragma unroll
    for (int dt = 0; dt < 8; dt++) {
      bf16x8 kf = *(const bf16x8*)(kbase + dt * 32);
      a = __builtin_amdgcn_mfma_f32_16x16x32_bf16(qf[dt], kf, a, 0, 0, 0);
    }
#pragma unroll
    for (int r = 0; r < 4; r++) {
      int qrow = l4 * 4 + r;          // query within tile
      int kcol = k0 + l15;            // global key
      float sv = a[r] * 0.0625f;      // HD^-0.5 = 1/16
      if (kcol > q0 + qrow) sv = -1e30f;
      sc[qrow][kcol] = sv;
    }
  }
  __syncthreads();

  // ---- softmax over rows; each wave owns 4 rows (16 lanes per row) ----
  const int nk = q0 + 16;             // written columns
  const int row = w * 4 + l4;
  float mx = -1e38f;
  for (int c = l15; c < nk; c += 16) mx = fmaxf(mx, sc[row][c]);
#pragma unroll
  for (int o = 8; o; o >>= 1) mx = fmaxf(mx, __shfl_xor(mx, o, 64));
  float sum = 0.f;
  for (int c = l15; c < nk; c += 16) {
    float e = __expf(sc[row][c] - mx);
    sc[row][c] = e;                   // unnormalized probs; 1/sum applied at epilogue
    sum += e;
  }
#pragma unroll
  for (int o = 8; o; o >>= 1) sum += __shfl_xor(sum, o, 64);
  if (l15 == 0) inv[row] = 1.f / sum;
  // zero-pad to 32-key MFMA granularity when (qt+1)*16 % 32 != 0
  if (!(qt & 1)) sc[row][nk + l15] = 0.f;
  __syncthreads();

  // ---- PV: wave owns d-range [w*64, w*64+64) ----
  f32x4 o_acc[4];
#pragma unroll
  for (int i = 0; i < 4; i++) o_acc[i] = (f32x4){0.f, 0.f, 0.f, 0.f};
  const int nchunks = (qt + 2) >> 1;  // ceil((qt+1)*16 / 32)
  for (int c32 = 0; c32 < nchunks; c32++) {
    int k0 = c32 * 32;
    bf16x8 pf;
#pragma unroll
    for (int j = 0; j < 8; j++)
      pf[j] = (bf16)sc[l15][k0 + l4 * 8 + j];
#pragma unroll
    for (int ni = 0; ni < 4; ni++) {
      bf16x8 vf;
#pragma unroll
      for (int j = 0; j < 8; j++)
        vf[j] = qkv[(size_t)(k0 + l4 * 8 + j) * D3 + 2 * DIM + h * HDIM + w * 64 + ni * 16 + l15];
      o_acc[ni] = __builtin_amdgcn_mfma_f32_16x16x32_bf16(pf, vf, o_acc[ni], 0, 0, 0);
    }
  }
#pragma unroll
  for (int ni = 0; ni < 4; ni++) {
#pragma unroll
    for (int r = 0; r < 4; r++) {
      int qrow = l4 * 4 + r;
      float val = o_acc[ni][r] * inv[qrow];
      attn[(size_t)(q0 + qrow) * DIM + h * HDIM + w * 64 + ni * 16 + l15] = (bf16)val;
    }
  }
}

// ---------------- launch ----------------
extern "C" void kernel_launch(void* const* d_in, const int* in_sizes, int n_in,
                              void* d_out, int out_size, void* d_ws, size_t ws_size,
                              hipStream_t stream)
{
  const float* hidden  = (const float*)d_in[0];
  const float* ln1w    = (const float*)d_in[1];
  const float* ln1b    = (const float*)d_in[2];
  const float* ln2w    = (const float*)d_in[3];
  const float* ln2b    = (const float*)d_in[4];
  const float* w_qkv   = (const float*)d_in[5];
  const float* b_qkv   = (const float*)d_in[6];
  const float* w_dense = (const float*)d_in[7];
  const float* b_dense = (const float*)d_in[8];
  const float* w_fc1   = (const float*)d_in[9];
  const float* b_fc1   = (const float*)d_in[10];
  const float* w_fc2   = (const float*)d_in[11];
  const float* b_fc2   = (const float*)d_in[12];

  char* ws = (char*)d_ws;
  bf16* x1        = (bf16*)(ws);                        // 16.78 MB
  bf16* x2        = (bf16*)(ws + 16777216);             // 16.78 MB
  bf16* qkv       = (bf16*)(ws + 33554432);             // 50.33 MB
  bf16* attn      = (bf16*)(ws + 83886080);             // 16.78 MB
  bf16* h1        = (bf16*)(ws + 100663296);            // 67.11 MB
  float* dense_o  = (float*)(ws + 167772160);           // 33.55 MB  (total 192 MB)
  float* out      = (float*)d_out;

  hipFuncSetAttribute(reinterpret_cast<const void*>(attn_kernel),
                      hipFuncAttributeMaxDynamicSharedMemorySize, 131264);

  ln_kernel<<<SEQ, 256, 0, stream>>>(hidden, ln1w, ln1b, ln2w, ln2b, x1, x2);

  // QKV: [2048,4096] x [4096,12288] -> qkv bf16
  gemm_kernel<0><<<dim3(16, 96), 256, 0, stream>>>(
      x1, w_qkv, b_qkv, nullptr, nullptr, (void*)qkv, SEQ, D3, DIM);

  attn_kernel<<<dim3(SEQ / 16, NHEAD), 256, 131264, stream>>>(qkv, attn);

  // dense: attn x [4096,4096] -> dense_o f32
  gemm_kernel<1><<<dim3(16, 32), 256, 0, stream>>>(
      attn, w_dense, b_dense, nullptr, nullptr, (void*)dense_o, SEQ, DIM, DIM);

  // fc1 + gelu: x2 x [4096,16384] -> h1 bf16
  gemm_kernel<2><<<dim3(16, 128), 256, 0, stream>>>(
      x2, w_fc1, b_fc1, nullptr, nullptr, (void*)h1, SEQ, DFF_N, DIM);

  // fc2 + residuals: h1 x [16384,4096] + dense_o + hidden -> out f32
  gemm_kernel<3><<<dim3(16, 32), 256, 0, stream>>>(
      h1, w_fc2, b_fc2, dense_o, hidden, (void*)out, SEQ, DIM, DFF_N);
}